// Round 5
// baseline (1540.180 us; speedup 1.0000x reference)
//
#include <hip/hip_runtime.h>
#include <math.h>

#define NN 10000
#define EE 320000
#define TILE 32
#define NB ((EE + 7 * NN + TILE - 1) / TILE)   // 12188 blocks, 390016 padded slots

constexpr float INVS32  = 0.17677669529663687f;   // 1/sqrt(32)
constexpr float INVS160 = 0.07905694150420949f;   // 1/sqrt(160)
constexpr float INVS96  = 0.10206207261596575f;   // 1/sqrt(96)
constexpr float INVS3   = 0.5773502691896258f;    // 1/sqrt(3)
constexpr float INVS2   = 0.7071067811865476f;    // 1/sqrt(2)
constexpr float LN2     = 0.6931471805599453f;

typedef short bf16x8 __attribute__((ext_vector_type(8)));
typedef float f32x4  __attribute__((ext_vector_type(4)));

__device__ __forceinline__ float sspf(float v) {
  return fmaxf(v, 0.f) + log1pf(expf(-fabsf(v))) - LN2;
}
__device__ __forceinline__ ushort f2bf(float f) {
  union { float f; unsigned u; } v; v.f = f;
  unsigned r = v.u + 0x7FFF + ((v.u >> 16) & 1);   // RNE
  return (ushort)(r >> 16);
}
__device__ __forceinline__ unsigned pk(float a, float b) {
  return (unsigned)f2bf(a) | ((unsigned)f2bf(b) << 16);
}
// unpack 8 bf16 (16B aligned) -> 8 f32; 1 VALU op per value
__device__ __forceinline__ void cvt8(const ushort* p, float* f) {
  uint4 u = *(const uint4*)p;
  f[0] = __uint_as_float(u.x << 16); f[1] = __uint_as_float(u.x & 0xFFFF0000u);
  f[2] = __uint_as_float(u.y << 16); f[3] = __uint_as_float(u.y & 0xFFFF0000u);
  f[4] = __uint_as_float(u.z << 16); f[5] = __uint_as_float(u.z & 0xFFFF0000u);
  f[6] = __uint_as_float(u.w << 16); f[7] = __uint_as_float(u.w & 0xFFFF0000u);
}

// ---------------- sort-by-dst kernels (runs padded to multiples of 8) ----------------
__global__ void hist_k(const int* __restrict__ ei, int* __restrict__ cnt) {
  int e = blockIdx.x * 256 + threadIdx.x;
  if (e < EE) atomicAdd(&cnt[ei[e]], 1);
}

__global__ __launch_bounds__(1024) void scan_k(const int* __restrict__ cnt,
                                               int* __restrict__ cursor) {
  __shared__ int s[1024];
  const int t = threadIdx.x;
  int loc[10];
  int sum = 0;
#pragma unroll
  for (int jj = 0; jj < 10; ++jj) {
    int idx = t * 10 + jj;
    int c = (idx < NN) ? ((cnt[idx] + 7) & ~7) : 0;   // 8-padded run length
    loc[jj] = sum;
    sum += c;
  }
  s[t] = sum;
  __syncthreads();
  for (int d = 1; d < 1024; d <<= 1) {
    int v = (t >= d) ? s[t - d] : 0;
    __syncthreads();
    s[t] += v;
    __syncthreads();
  }
  const int excl = (t > 0) ? s[t - 1] : 0;
#pragma unroll
  for (int jj = 0; jj < 10; ++jj) {
    int idx = t * 10 + jj;
    if (idx < NN) cursor[idx] = excl + loc[jj];
  }
}

__global__ void scat_k(const int* __restrict__ ei, int* __restrict__ cursor,
                       int* __restrict__ order8) {
  int e = blockIdx.x * 256 + threadIdx.x;
  if (e < EE) {
    int p = atomicAdd(&cursor[ei[e]], 1);
    order8[p] = e;
  }
}

// ---------------- weight transforms: F2T/L2T bf16 (scale folded), WO*T f32 ----------------
__global__ void prep_t_k(const float* __restrict__ F2, const float* __restrict__ L2,
                         const float* __restrict__ WO0, const float* __restrict__ WO1,
                         const float* __restrict__ WO2,
                         ushort* __restrict__ F2Tb, ushort* __restrict__ L2Tb,
                         float* __restrict__ WO0T, float* __restrict__ WO1T,
                         float* __restrict__ WO2T) {
  int i = blockIdx.x * 256 + threadIdx.x;
  if (i < 7168) {                         // F2T/L2T: [c][k] bf16
    int c = i >> 5, k = i & 31;
    float sc = (c < 64)  ? (1.f / 32.f)
             : (c < 128) ? (INVS3 / 32.f)
             : (c < 160) ? (1.f / 32.f)
             : (c < 192) ? (INVS3 / 32.f)
                         : (INVS2 / 32.f);
    F2Tb[i] = f2bf(F2[k * 224 + c] * sc);
    L2Tb[i] = f2bf(L2[k * 224 + c]);
  } else if (i < 7168 + 12288) {          // WO0T [128][96], scale folded
    int j = i - 7168; int k = j / 96, u = j - k * 96;
    WO0T[j] = WO0[u * 128 + k] * INVS96;
  } else if (i < 7168 + 12288 + 6144) {   // WO1T [64][96]
    int j = i - 7168 - 12288; int v = j / 96, u = j - v * 96;
    WO1T[j] = WO1[u * 64 + v] * INVS96;
  } else if (i < 7168 + 12288 + 6144 + 1024) {  // WO2T [32][32]
    int j = i - 7168 - 12288 - 6144; int v = j >> 5, u = j & 31;
    WO2T[j] = WO2[u * 32 + v] * INVS32;
  }
}

// ---------------- node-level precompute (4-partial ILP dots) ----------------
__global__ __launch_bounds__(256) void node_prep_k(
    const float* __restrict__ x,
    const float* __restrict__ W0p, const float* __restrict__ b0p,
    const float* __restrict__ W1p,
    const float* __restrict__ W0n, const float* __restrict__ b0n,
    const float* __restrict__ W1n,
    const float* __restrict__ G1, const float* __restrict__ g1b,
    const float* __restrict__ G2, const float* __restrict__ g2b,
    const float* __restrict__ L1,
    float* __restrict__ p1w, float* __restrict__ x0nw, float* __restrict__ x1nw,
    float* __restrict__ Aw, float* __restrict__ Bw)
{
  const int wv   = threadIdx.x >> 6;
  const int lane = threadIdx.x & 63;
  const int n    = blockIdx.x * 4 + wv;
  const bool nv  = (n < NN);

  __shared__ float sX[4][160];
  __shared__ float sP0[4][64];
  __shared__ float sF0[4][96];
  __shared__ float sH1[4][96];
  __shared__ float sG[4][96];

  if (nv) {
    sX[wv][lane]      = x[n * 160 + lane];
    sX[wv][lane + 64] = x[n * 160 + lane + 64];
    if (lane < 32) sX[wv][lane + 128] = x[n * 160 + lane + 128];
  }
  __syncthreads();

  if (nv) {
    {
      float d0 = 0.f, d1 = 0.f, d2 = 0.f, d3 = 0.f;
      for (int i = 0; i < 64; i += 4) {
        d0 = fmaf(sX[wv][i],     W0p[i * 64 + lane],       d0);
        d1 = fmaf(sX[wv][i + 1], W0p[(i + 1) * 64 + lane], d1);
        d2 = fmaf(sX[wv][i + 2], W0p[(i + 2) * 64 + lane], d2);
        d3 = fmaf(sX[wv][i + 3], W0p[(i + 3) * 64 + lane], d3);
      }
      sP0[wv][lane] = ((d0 + d1) + (d2 + d3)) * 0.125f + b0p[lane];
      sF0[wv][lane] = sX[wv][lane];
    }
    for (int o = lane; o < 96; o += 64) {
      const int v = o / 3, i_ = o % 3;
      float d0 = 0.f, d1 = 0.f;
      for (int u = 0; u < 32; u += 2) {
        d0 = fmaf(sX[wv][64 + u * 3 + i_],       W1p[u * 32 + v],       d0);
        d1 = fmaf(sX[wv][64 + (u + 1) * 3 + i_], W1p[(u + 1) * 32 + v], d1);
      }
      p1w[n * 96 + o] = (d0 + d1) * INVS32;
    }
    if (lane < 32) {
      float s2 = 1e-12f;
#pragma unroll
      for (int i = 0; i < 3; ++i) { float t = sX[wv][64 + lane * 3 + i]; s2 += t * t; }
      sF0[wv][64 + lane] = sqrtf(s2);
    }
  }
  __syncthreads();

  if (nv) for (int o = lane; o < 96; o += 64) {
    float d0 = g1b[o], d1 = 0.f, d2 = 0.f, d3 = 0.f;
    for (int i = 0; i < 96; i += 4) {
      d0 = fmaf(sF0[wv][i],     G1[i * 96 + o],       d0);
      d1 = fmaf(sF0[wv][i + 1], G1[(i + 1) * 96 + o], d1);
      d2 = fmaf(sF0[wv][i + 2], G1[(i + 2) * 96 + o], d2);
      d3 = fmaf(sF0[wv][i + 3], G1[(i + 3) * 96 + o], d3);
    }
    float d = (d0 + d1) + (d2 + d3);
    sH1[wv][o] = d / (1.f + expf(-d));
  }
  __syncthreads();

  if (nv) for (int o = lane; o < 96; o += 64) {
    float d0 = g2b[o], d1 = 0.f, d2 = 0.f, d3 = 0.f;
    for (int i = 0; i < 96; i += 4) {
      d0 = fmaf(sH1[wv][i],     G2[i * 96 + o],       d0);
      d1 = fmaf(sH1[wv][i + 1], G2[(i + 1) * 96 + o], d1);
      d2 = fmaf(sH1[wv][i + 2], G2[(i + 2) * 96 + o], d2);
      d3 = fmaf(sH1[wv][i + 3], G2[(i + 3) * 96 + o], d3);
    }
    sG[wv][o] = (d0 + d1) + (d2 + d3);
  }
  __syncthreads();

  if (nv) {
    {
      float d0 = 0.f, d1 = 0.f, d2 = 0.f, d3 = 0.f;
      for (int i = 0; i < 64; i += 4) {
        d0 = fmaf(sG[wv][i],     W0n[i * 64 + lane],       d0);
        d1 = fmaf(sG[wv][i + 1], W0n[(i + 1) * 64 + lane], d1);
        d2 = fmaf(sG[wv][i + 2], W0n[(i + 2) * 64 + lane], d2);
        d3 = fmaf(sG[wv][i + 3], W0n[(i + 3) * 64 + lane], d3);
      }
      x0nw[n * 64 + lane] = ((d0 + d1) + (d2 + d3)) * 0.125f + b0n[lane];
    }
    for (int o = lane; o < 96; o += 64) {
      const int v = o / 3, i_ = o % 3;
      float d0 = 0.f, d1 = 0.f;
      for (int u = 0; u < 32; u += 2) {
        d0 = fmaf(sX[wv][64 + u * 3 + i_] * sG[wv][64 + u],
                  W1n[u * 32 + v], d0);
        d1 = fmaf(sX[wv][64 + (u + 1) * 3 + i_] * sG[wv][64 + u + 1],
                  W1n[(u + 1) * 32 + v], d1);
      }
      x1nw[n * 96 + o] = (d0 + d1) * INVS32;
    }
    if (lane < 32) {
      float a0 = 0.f, a1 = 0.f, b0 = 0.f, b1 = 0.f;
      for (int i = 0; i < 64; i += 2) {
        a0 = fmaf(sP0[wv][i],     L1[i * 32 + lane],         a0);
        a1 = fmaf(sP0[wv][i + 1], L1[(i + 1) * 32 + lane],   a1);
        b0 = fmaf(sP0[wv][i],     L1[(64 + i) * 32 + lane],  b0);
        b1 = fmaf(sP0[wv][i + 1], L1[(65 + i) * 32 + lane],  b1);
      }
      Aw[n * 32 + lane] = (a0 + a1) * INVS160;
      Bw[n * 32 + lane] = (b0 + b1) * INVS160;
    }
  }
}

// ---------------- fused per-edge MLP (MFMA) + transposed scatter ----------------
__global__ __launch_bounds__(256, 3) void fused_edge_k(
    const float* __restrict__ edge_attr,
    const float* __restrict__ edge_sh,
    const int* __restrict__ ei,
    const float* __restrict__ F1, const float* __restrict__ L1,
    const ushort* __restrict__ F2Tb, const ushort* __restrict__ L2Tb,
    const float* __restrict__ p1w, const float* __restrict__ Aw,
    const float* __restrict__ Bw,
    const float* __restrict__ x0nw, const float* __restrict__ x1nw,
    const int* __restrict__ order8,
    float* __restrict__ o480)
{
  const int s0  = blockIdx.x * TILE;
  const int tid = threadIdx.x;

  if (order8[s0] < 0) return;   // wholly past padded end (uniform, see scan/pad proof)

  // sWT: f32 [224][36] (channel-major, rows 144B -> b128-aligned, conflict-free reads)
  __shared__ __align__(16) float sWT[224 * 36];                  // 32256 B
  float (*sEA)[36] = (float (*)[36])sWT;                         // union (dead after B)
  float (*sIP)[36] = (float (*)[36])(sWT + 32 * 36);
  __shared__ ushort sX0T[64 * 40];   // bf16 channel-major, rows 80B
  __shared__ ushort sX1T[96 * 40];
  __shared__ ushort sSHT[4 * 40];
  __shared__ ushort sHF[32 * 40];    // bf16 [edge][32+pad]
  __shared__ ushort sHL[32 * 40];
  __shared__ int    sDst[32];

  const int g = tid >> 3, l = tid & 7;   // 8 threads per edge slot
  const int eo  = order8[s0 + g];
  const bool valid = (eo >= 0);
  const int e   = valid ? eo : 0;
  const int dst = ei[e];
  const int src = ei[EE + e];
  if (l == 0) sDst[g] = valid ? dst : -1;

  // ---- phase A: stage (transposed bf16 for xs/sh; f32 for ea/ip) ----
  *(float4*)&sEA[g][l * 4] = *(const float4*)(edge_attr + (size_t)e * 32 + l * 4);
  if (l < 4) sSHT[l * 40 + g] = f2bf(edge_sh[(size_t)e * 4 + l]);
#pragma unroll
  for (int j = 0; j < 8; ++j)
    sX0T[(l + 8 * j) * 40 + g] = f2bf(x0nw[(size_t)src * 64 + l + 8 * j]);
#pragma unroll
  for (int j = 0; j < 12; ++j)
    sX1T[(l + 8 * j) * 40 + g] = f2bf(x1nw[(size_t)src * 96 + l + 8 * j]);
  {
    const float4* pd = (const float4*)(p1w + (size_t)dst * 96 + l * 12);
    const float4* ps = (const float4*)(p1w + (size_t)src * 96 + l * 12);
    float dp[12], sp[12];
#pragma unroll
    for (int k = 0; k < 3; ++k) {
      float4 v = pd[k]; dp[4*k] = v.x; dp[4*k+1] = v.y; dp[4*k+2] = v.z; dp[4*k+3] = v.w;
      float4 u = ps[k]; sp[4*k] = u.x; sp[4*k+1] = u.y; sp[4*k+2] = u.z; sp[4*k+3] = u.w;
    }
#pragma unroll
    for (int vv = 0; vv < 4; ++vv) {
      const int b = 3 * vv;
      sIP[g][l * 4 + vv] =
        (dp[b] * sp[b] + dp[b+1] * sp[b+1] + dp[b+2] * sp[b+2]) * INVS3;
    }
  }
  __syncthreads();

  // ---- phase B: hidden layers -> bf16 LDS (zeroed for pad slots) ----
  {
    const bool vf = (sDst[g] >= 0);
    float hfa[4] = {0.f, 0.f, 0.f, 0.f};
    float hla[4] = {0.f, 0.f, 0.f, 0.f};
    for (int c = 0; c < 32; ++c) {
      const float eac = sEA[g][c];
      const float ipc = sIP[g][c];
      const float4 f  = *(const float4*)(F1 + c * 32 + l * 4);
      const float4 lc = *(const float4*)(L1 + (128 + c) * 32 + l * 4);
      hfa[0] = fmaf(eac, f.x, hfa[0]);  hfa[1] = fmaf(eac, f.y, hfa[1]);
      hfa[2] = fmaf(eac, f.z, hfa[2]);  hfa[3] = fmaf(eac, f.w, hfa[3]);
      hla[0] = fmaf(ipc, lc.x, hla[0]); hla[1] = fmaf(ipc, lc.y, hla[1]);
      hla[2] = fmaf(ipc, lc.z, hla[2]); hla[3] = fmaf(ipc, lc.w, hla[3]);
    }
    const float4 av = *(const float4*)(Aw + (size_t)dst * 32 + l * 4);
    const float4 bv = *(const float4*)(Bw + (size_t)src * 32 + l * 4);
    const float f0 = vf ? sspf(hfa[0] * INVS32) : 0.f;
    const float f1 = vf ? sspf(hfa[1] * INVS32) : 0.f;
    const float f2 = vf ? sspf(hfa[2] * INVS32) : 0.f;
    const float f3 = vf ? sspf(hfa[3] * INVS32) : 0.f;
    const float l0 = vf ? sspf(av.x + bv.x + hla[0] * INVS160) : 0.f;
    const float l1v = vf ? sspf(av.y + bv.y + hla[1] * INVS160) : 0.f;
    const float l2v = vf ? sspf(av.z + bv.z + hla[2] * INVS160) : 0.f;
    const float l3v = vf ? sspf(av.w + bv.w + hla[3] * INVS160) : 0.f;
    *(unsigned*)&sHF[g * 40 + l * 4 + 0] = pk(f0, f1);
    *(unsigned*)&sHF[g * 40 + l * 4 + 2] = pk(f2, f3);
    *(unsigned*)&sHL[g * 40 + l * 4 + 0] = pk(l0, l1v);
    *(unsigned*)&sHL[g * 40 + l * 4 + 2] = pk(l2v, l3v);
  }
  __syncthreads();

  // ---- phase C: MFMA w-GEMMs -> sWT f32 (scales folded in F2Tb) ----
  {
    const int wvi  = tid >> 6;
    const int lane = tid & 63;
    const int r = lane & 15;
    const int h = lane >> 4;
    bf16x8 aF0 = *(const bf16x8*)&sHF[r * 40 + h * 8];
    bf16x8 aF1 = *(const bf16x8*)&sHF[(16 + r) * 40 + h * 8];
    bf16x8 aL0 = *(const bf16x8*)&sHL[r * 40 + h * 8];
    bf16x8 aL1 = *(const bf16x8*)&sHL[(16 + r) * 40 + h * 8];
    const int ct0 = (wvi < 2) ? wvi * 4 : 8 + (wvi - 2) * 3;
    const int nct = (wvi < 2) ? 4 : 3;
    for (int t = 0; t < nct; ++t) {
      const int c = (ct0 + t) * 16 + r;
      bf16x8 bF = *(const bf16x8*)&F2Tb[c * 32 + h * 8];
      bf16x8 bL = *(const bf16x8*)&L2Tb[c * 32 + h * 8];
      f32x4 z = {0.f, 0.f, 0.f, 0.f};
      f32x4 wf0 = __builtin_amdgcn_mfma_f32_16x16x32_bf16(aF0, bF, z, 0, 0, 0);
      f32x4 wl0 = __builtin_amdgcn_mfma_f32_16x16x32_bf16(aL0, bL, z, 0, 0, 0);
      f32x4 wf1 = __builtin_amdgcn_mfma_f32_16x16x32_bf16(aF1, bF, z, 0, 0, 0);
      f32x4 wl1 = __builtin_amdgcn_mfma_f32_16x16x32_bf16(aL1, bL, z, 0, 0, 0);
#pragma unroll
      for (int i = 0; i < 4; ++i) {
        sWT[c * 36 + h * 4 + i]      = wf0[i] * wl0[i];
        sWT[c * 36 + 16 + h * 4 + i] = wf1[i] * wl1[i];
      }
    }
  }
  __syncthreads();

  // ---- phase D: vectorized 8-edge-subgroup accumulate + boundary flush ----
  {
    // decode both channel jobs once
    int mode[2]; const float* wr[2];
    const ushort *xa[2], *xb[2], *sa[2], *sb[2];
#pragma unroll
    for (int jj = 0; jj < 2; ++jj) {
      const int k = tid + jj * 256;
      if (jj == 1 && tid >= 224) { mode[jj] = -1; continue; }
      if (k < 64) {
        mode[jj] = 0; wr[jj] = sWT + k * 36;
        xa[jj] = sX0T + k * 40; sa[jj] = sSHT;
      } else if (k < 96) {
        const int c = k - 64;
        mode[jj] = 1; wr[jj] = sWT + (160 + c) * 36;
        xa[jj] = sX1T + (3 * c) * 40; sa[jj] = sSHT + 40;
      } else if (k < 288) {
        const int kk = k - 96; const int u = kk / 3; const int i = kk - 3 * u;
        mode[jj] = 0; wr[jj] = sWT + (64 + u) * 36;
        xa[jj] = sX0T + u * 40; sa[jj] = sSHT + (1 + i) * 40;
      } else if (k < 384) {
        const int kk = k - 288; const int u = kk / 3; const int i = kk - 3 * u;
        mode[jj] = 0; wr[jj] = sWT + (128 + u) * 36;
        xa[jj] = sX1T + (3 * u + i) * 40; sa[jj] = sSHT;
      } else {
        const int kk = k - 384; const int u = kk / 3; const int i = kk - 3 * u;
        const int i1 = (i + 1) % 3, i2 = (i + 2) % 3;
        mode[jj] = 2; wr[jj] = sWT + (192 + u) * 36;
        xa[jj] = sX1T + (3 * u + i1) * 40; xb[jj] = sX1T + (3 * u + i2) * 40;
        sa[jj] = sSHT + (1 + i2) * 40;     sb[jj] = sSHT + (1 + i1) * 40;
      }
    }

    float acc[2] = {0.f, 0.f};
    auto accum8 = [&](int jj, int q0) {
      float w[8];
      { f32x4 w0 = *(const f32x4*)(wr[jj] + q0);
        f32x4 w1 = *(const f32x4*)(wr[jj] + q0 + 4);
        w[0]=w0[0]; w[1]=w0[1]; w[2]=w0[2]; w[3]=w0[3];
        w[4]=w1[0]; w[5]=w1[1]; w[6]=w1[2]; w[7]=w1[3]; }
      if (mode[jj] == 0) {
        float xv[8], sv[8];
        cvt8(xa[jj] + q0, xv); cvt8(sa[jj] + q0, sv);
        float a = acc[jj];
#pragma unroll
        for (int j = 0; j < 8; ++j) a = fmaf(w[j] * xv[j], sv[j], a);
        acc[jj] = a;
      } else if (mode[jj] == 1) {
        float x0[8], x1[8], x2[8], s1[8], s2[8], s3[8];
        cvt8(xa[jj] + q0, x0); cvt8(xa[jj] + 40 + q0, x1); cvt8(xa[jj] + 80 + q0, x2);
        cvt8(sa[jj] + q0, s1); cvt8(sa[jj] + 40 + q0, s2); cvt8(sa[jj] + 80 + q0, s3);
        float a = acc[jj];
#pragma unroll
        for (int j = 0; j < 8; ++j) {
          float d = fmaf(x2[j], s3[j], fmaf(x1[j], s2[j], x0[j] * s1[j]));
          a = fmaf(w[j], d, a);
        }
        acc[jj] = a;
      } else {
        float xav[8], xbv[8], sav[8], sbv[8];
        cvt8(xa[jj] + q0, xav); cvt8(xb[jj] + q0, xbv);
        cvt8(sa[jj] + q0, sav); cvt8(sb[jj] + q0, sbv);
        float a = acc[jj];
#pragma unroll
        for (int j = 0; j < 8; ++j) {
          float cr = fmaf(xav[j], sav[j], -(xbv[j] * sbv[j]));
          a = fmaf(w[j], cr, a);
        }
        acc[jj] = a;
      }
    };

    for (int sg = 0; sg < 4; ++sg) {
      const int q0 = sg * 8;
      accum8(0, q0);
      if (mode[1] >= 0) accum8(1, q0);
      const int d = sDst[sg * 8];
      const bool fl = (sg == 3) || (sDst[sg * 8 + 8] != d);
      if (fl) {
        if (d >= 0) {
          float* dp = o480 + (size_t)d * 480;
          atomicAdd(dp + tid, acc[0]);
          if (mode[1] >= 0) atomicAdd(dp + tid + 256, acc[1]);
        }
        acc[0] = 0.f; acc[1] = 0.f;
      }
    }
  }
}

// ---------------- final output linears (transposed weights, 4-partial dots) ----------------
__global__ __launch_bounds__(256) void out_wo_k(
    const float* __restrict__ o480,
    const float* __restrict__ WO0T, const float* __restrict__ WO1T,
    const float* __restrict__ WO2T, const float* __restrict__ bO0,
    float* __restrict__ out)
{
  const int wv = threadIdx.x >> 6, lane = threadIdx.x & 63;
  const int n = blockIdx.x * 4 + wv;
  __shared__ float sO[4][480];
  if (n < NN) {
    const float4* src = (const float4*)(o480 + (size_t)n * 480);
    for (int idx = lane; idx < 120; idx += 64)
      *(float4*)&sO[wv][idx * 4] = src[idx];
  }
  __syncthreads();
  if (n >= NN) return;
  const float* so = sO[wv];
  for (int k = lane; k < 416; k += 64) {
    float y;
    if (k < 128) {
      const float4* wr4 = (const float4*)(WO0T + k * 96);
      float a0 = 0.f, a1 = 0.f, a2 = 0.f, a3 = 0.f;
#pragma unroll
      for (int ch = 0; ch < 24; ch += 4) {
        float4 w0 = wr4[ch], w1 = wr4[ch+1], w2 = wr4[ch+2], w3 = wr4[ch+3];
        a0 = fmaf(w0.x, so[ch*4+0], fmaf(w0.y, so[ch*4+1], fmaf(w0.z, so[ch*4+2], fmaf(w0.w, so[ch*4+3], a0))));
        a1 = fmaf(w1.x, so[ch*4+4], fmaf(w1.y, so[ch*4+5], fmaf(w1.z, so[ch*4+6], fmaf(w1.w, so[ch*4+7], a1))));
        a2 = fmaf(w2.x, so[ch*4+8], fmaf(w2.y, so[ch*4+9], fmaf(w2.z, so[ch*4+10], fmaf(w2.w, so[ch*4+11], a2))));
        a3 = fmaf(w3.x, so[ch*4+12], fmaf(w3.y, so[ch*4+13], fmaf(w3.z, so[ch*4+14], fmaf(w3.w, so[ch*4+15], a3))));
      }
      y = ((a0 + a1) + (a2 + a3)) + bO0[k];
    } else if (k < 320) {
      const int kk = k - 128; const int v = kk / 3; const int i = kk - 3 * v;
      const float* wr = WO1T + v * 96;
      const float* sb = so + 96 + i;
      float a0 = 0.f, a1 = 0.f, a2 = 0.f, a3 = 0.f;
#pragma unroll
      for (int u = 0; u < 96; u += 4) {
        a0 = fmaf(wr[u],     sb[u * 3],       a0);
        a1 = fmaf(wr[u + 1], sb[(u + 1) * 3], a1);
        a2 = fmaf(wr[u + 2], sb[(u + 2) * 3], a2);
        a3 = fmaf(wr[u + 3], sb[(u + 3) * 3], a3);
      }
      y = (a0 + a1) + (a2 + a3);
    } else {
      const int kk = k - 320; const int v = kk / 3; const int i = kk - 3 * v;
      const float* wr = WO2T + v * 32;
      const float* sb = so + 384 + i;
      float a0 = 0.f, a1 = 0.f, a2 = 0.f, a3 = 0.f;
#pragma unroll
      for (int u = 0; u < 32; u += 4) {
        a0 = fmaf(wr[u],     sb[u * 3],       a0);
        a1 = fmaf(wr[u + 1], sb[(u + 1) * 3], a1);
        a2 = fmaf(wr[u + 2], sb[(u + 2) * 3], a2);
        a3 = fmaf(wr[u + 3], sb[(u + 3) * 3], a3);
      }
      y = (a0 + a1) + (a2 + a3);
    }
    out[(size_t)n * 416 + k] = y;
  }
}

// ---------------- host ----------------
extern "C" void kernel_launch(void* const* d_in, const int* in_sizes, int n_in,
                              void* d_out, int out_size, void* d_ws, size_t ws_size,
                              hipStream_t stream) {
  const float* x         = (const float*)d_in[0];
  const float* edge_sh   = (const float*)d_in[1];
  const float* edge_attr = (const float*)d_in[2];
  const float* W0p       = (const float*)d_in[3];
  const float* b0p       = (const float*)d_in[4];
  const float* W1p       = (const float*)d_in[5];
  const float* W0n       = (const float*)d_in[6];
  const float* b0n       = (const float*)d_in[7];
  const float* W1n       = (const float*)d_in[8];
  const float* G1        = (const float*)d_in[9];
  const float* g1b       = (const float*)d_in[10];
  const float* G2        = (const float*)d_in[11];
  const float* g2b       = (const float*)d_in[12];
  const float* F1        = (const float*)d_in[13];
  const float* F2        = (const float*)d_in[14];
  const float* L1        = (const float*)d_in[15];
  const float* L2        = (const float*)d_in[16];
  const float* WO0       = (const float*)d_in[17];
  const float* bO0       = (const float*)d_in[18];
  const float* WO1       = (const float*)d_in[19];
  const float* WO2       = (const float*)d_in[20];
  const int*   ei        = (const int*)d_in[21];
  float* out = (float*)d_out;

  float* p1w  = (float*)d_ws;          // N*96
  float* x0nw = p1w  + NN * 96;        // N*64
  float* x1nw = x0nw + NN * 64;        // N*96
  float* Aw   = x1nw + NN * 96;        // N*32
  float* Bw   = Aw   + NN * 32;        // N*32
  float* o480 = Bw   + NN * 32;        // N*480
  int* cnt    = (int*)(o480 + (size_t)NN * 480);
  int* cursor = cnt    + NN;
  int* order8 = cursor + NN;           // NB*TILE padded slots
  uintptr_t p = (uintptr_t)(order8 + NB * TILE);
  p = (p + 15) & ~(uintptr_t)15;
  ushort* F2Tb = (ushort*)p;           // 224*32 bf16
  ushort* L2Tb = F2Tb + 224 * 32;
  uintptr_t p2 = (uintptr_t)(L2Tb + 224 * 32);
  p2 = (p2 + 15) & ~(uintptr_t)15;
  float* WO0T = (float*)p2;            // 128*96
  float* WO1T = WO0T + 128 * 96;       // 64*96
  float* WO2T = WO1T + 64 * 96;        // 32*32

  hipMemsetAsync(cnt, 0, NN * sizeof(int), stream);
  hipMemsetAsync(o480, 0, (size_t)NN * 480 * sizeof(float), stream);
  hipMemsetAsync(order8, 0xFF, (size_t)NB * TILE * sizeof(int), stream);
  prep_t_k<<<104, 256, 0, stream>>>(F2, L2, WO0, WO1, WO2,
                                    F2Tb, L2Tb, WO0T, WO1T, WO2T);
  hist_k<<<(EE + 255) / 256, 256, 0, stream>>>(ei, cnt);
  scan_k<<<1, 1024, 0, stream>>>(cnt, cursor);
  scat_k<<<(EE + 255) / 256, 256, 0, stream>>>(ei, cursor, order8);
  node_prep_k<<<(NN + 3) / 4, 256, 0, stream>>>(x, W0p, b0p, W1p, W0n, b0n, W1n,
                                                G1, g1b, G2, g2b, L1,
                                                p1w, x0nw, x1nw, Aw, Bw);
  fused_edge_k<<<NB, 256, 0, stream>>>(edge_attr, edge_sh, ei,
                                       F1, L1, F2Tb, L2Tb,
                                       p1w, Aw, Bw, x0nw, x1nw,
                                       order8, o480);
  out_wo_k<<<(NN + 3) / 4, 256, 0, stream>>>(o480, WO0T, WO1T, WO2T, bO0, out);
}